// Round 2
// baseline (696.226 us; speedup 1.0000x reference)
//
#include <hip/hip_runtime.h>
#include <math.h>

// FusionNeRF round 4:
//   - Round-3 post-mortem: af[2][4]/bf[2][4] prefetch arrays were scratch-allocated
//     (rule: runtime-ish indexed ext_vector arrays -> local mem). Evidence:
//     WRITE_SIZE 5MB->114MB (scratch writeback), VGPR stuck at 84, occupancy 32->23.
//   - Fix: double-buffer with NAMED scalar short8 regs, rotated at end of each
//     fully-unrolled kk iteration (SSA renames, no moves, no scratch).
//   - Keeps round-3 wins: swapped MFMA operands (lane C-frag = 4 consecutive
//     features of one sample -> float4 bias + 2x v_cvt_pk_bf16_f32 + ds_write_b64
//     epilogue), sincosf-paired encoding.

#define RAYS 2048
#define SAMP 128
#define MTOT (RAYS * SAMP)
#define HD   256
#define BM   64              // samples per block
#define ES   136             // enc LDS stride (bf16), Kpad=128 (+8 pad)
#define HS   264             // hidden LDS stride (bf16), 256 (+8 pad)

// output float offsets
#define OUT_RGB   0
#define OUT_DEPTH 6144
#define OUT_W     8192
#define OUT_SW    270336
#define OUT_DW    532480

// bf16 weight workspace offsets (elements)
#define SW0 0
#define SW1 32768
#define SW2 98304
#define SW3 163840
#define SW4 229376
#define DW0 233472
#define DW1 266240
#define DW2 331776
#define DW3 397312
#define DW4 462848
#define WTOT 466944

typedef __attribute__((ext_vector_type(8))) short short8;
typedef __attribute__((ext_vector_type(4))) float f32x4;
typedef __attribute__((ext_vector_type(2))) unsigned int uint2v;

__device__ __forceinline__ float sigm(float x) { return 1.0f / (1.0f + expf(-x)); }

__device__ __forceinline__ short f2bf(float f) {   // RNE fp32 -> bf16
    union { float f; unsigned u; } v; v.f = f;
    unsigned r = v.u + 0x7fffu + ((v.u >> 16) & 1u);
    return (short)(r >> 16);
}

// ---------------- weight prep: W[K][N] fp32 -> Wt[Npad][Kpad] bf16 ----------------
__device__ __forceinline__ void conv1(const float* __restrict__ src, short* __restrict__ dst,
                                      int local, int K, int N, int Kpad) {
    const int n = local / Kpad, k = local - n * Kpad;
    const float v = (k < K && n < N) ? src[k * N + n] : 0.0f;
    dst[local] = f2bf(v);
}

__global__ __launch_bounds__(256)
void prep_weights(const float* sW0, const float* sW1, const float* sW2,
                  const float* sW3, const float* sW4,
                  const float* dW0, const float* dW1, const float* dW2,
                  const float* dW3, const float* dW4, short* __restrict__ dst)
{
    const int idx = blockIdx.x * 256 + threadIdx.x;
    if (idx >= WTOT) return;
    if      (idx < SW1) conv1(sW0, dst + SW0, idx - SW0,  90, 256, 128);
    else if (idx < SW2) conv1(sW1, dst + SW1, idx - SW1, 256, 256, 256);
    else if (idx < SW3) conv1(sW2, dst + SW2, idx - SW2, 256, 256, 256);
    else if (idx < SW4) conv1(sW3, dst + SW3, idx - SW3, 256, 256, 256);
    else if (idx < DW0) conv1(sW4, dst + SW4, idx - SW4, 256,   4, 256);
    else if (idx < DW1) conv1(dW0, dst + DW0, idx - DW0,  99, 256, 128);
    else if (idx < DW2) conv1(dW1, dst + DW1, idx - DW1, 256, 256, 256);
    else if (idx < DW3) conv1(dW2, dst + DW2, idx - DW2, 256, 256, 256);
    else if (idx < DW4) conv1(dW3, dst + DW3, idx - DW3, 256, 256, 256);
    else                conv1(dW4, dst + DW4, idx - DW4, 256,   5, 256);
}

// ---------------- MFMA dense layer (swapped operands, named-reg double buffer) ----
// A-operand = weights Wt[256][K] (global, k-contiguous), B-operand = acts [64][K] (LDS).
// Wave w owns output features [64w, 64w+64). C lane fragment = 4 consecutive
// features (qq*4+i) of sample col -> packed b64 store. A may alias O (internal barrier).
template <int KSTEPS, bool RELU>
__device__ __forceinline__ void layer256(const short* A, int As,
                                         const short* __restrict__ Wt,
                                         const float* __restrict__ bias,
                                         short* O, int Os, int tid)
{
    const int w = tid >> 6, lane = tid & 63, qq = lane >> 4, col = lane & 15;
    const int K = KSTEPS * 32;

    f32x4 acc[4][4];   // acc[ft][st]: features ft*16.., samples st*16.. (const-indexed)
#pragma unroll
    for (int ft = 0; ft < 4; ft++)
#pragma unroll
        for (int st = 0; st < 4; st++) acc[ft][st] = (f32x4)0.0f;

    const short* wbase = Wt + (size_t)(w * 64 + col) * K + qq * 8;  // a: feat row = w*64+ft*16+col
    const short* abase = A + (size_t)col * As + qq * 8;             // b: samp row = st*16+col

    // current fragments (named scalars -> guaranteed VGPRs)
    short8 wa0 = *(const short8*)(wbase + (size_t)0 * 16 * K);
    short8 wa1 = *(const short8*)(wbase + (size_t)1 * 16 * K);
    short8 wa2 = *(const short8*)(wbase + (size_t)2 * 16 * K);
    short8 wa3 = *(const short8*)(wbase + (size_t)3 * 16 * K);
    short8 ba0 = *(const short8*)(abase + 0 * 16 * As);
    short8 ba1 = *(const short8*)(abase + 1 * 16 * As);
    short8 ba2 = *(const short8*)(abase + 2 * 16 * As);
    short8 ba3 = *(const short8*)(abase + 3 * 16 * As);

#pragma unroll
    for (int kk = 0; kk < KSTEPS; kk++) {
        short8 na0, na1, na2, na3, nb0, nb1, nb2, nb3;
        if (kk + 1 < KSTEPS) {           // prefetch kk+1 while MFMA consumes kk
            const int ko = (kk + 1) * 32;
            na0 = *(const short8*)(wbase + (size_t)0 * 16 * K + ko);
            na1 = *(const short8*)(wbase + (size_t)1 * 16 * K + ko);
            na2 = *(const short8*)(wbase + (size_t)2 * 16 * K + ko);
            na3 = *(const short8*)(wbase + (size_t)3 * 16 * K + ko);
            nb0 = *(const short8*)(abase + 0 * 16 * As + ko);
            nb1 = *(const short8*)(abase + 1 * 16 * As + ko);
            nb2 = *(const short8*)(abase + 2 * 16 * As + ko);
            nb3 = *(const short8*)(abase + 3 * 16 * As + ko);
        }
        acc[0][0] = __builtin_amdgcn_mfma_f32_16x16x32_bf16(wa0, ba0, acc[0][0], 0, 0, 0);
        acc[0][1] = __builtin_amdgcn_mfma_f32_16x16x32_bf16(wa0, ba1, acc[0][1], 0, 0, 0);
        acc[0][2] = __builtin_amdgcn_mfma_f32_16x16x32_bf16(wa0, ba2, acc[0][2], 0, 0, 0);
        acc[0][3] = __builtin_amdgcn_mfma_f32_16x16x32_bf16(wa0, ba3, acc[0][3], 0, 0, 0);
        acc[1][0] = __builtin_amdgcn_mfma_f32_16x16x32_bf16(wa1, ba0, acc[1][0], 0, 0, 0);
        acc[1][1] = __builtin_amdgcn_mfma_f32_16x16x32_bf16(wa1, ba1, acc[1][1], 0, 0, 0);
        acc[1][2] = __builtin_amdgcn_mfma_f32_16x16x32_bf16(wa1, ba2, acc[1][2], 0, 0, 0);
        acc[1][3] = __builtin_amdgcn_mfma_f32_16x16x32_bf16(wa1, ba3, acc[1][3], 0, 0, 0);
        acc[2][0] = __builtin_amdgcn_mfma_f32_16x16x32_bf16(wa2, ba0, acc[2][0], 0, 0, 0);
        acc[2][1] = __builtin_amdgcn_mfma_f32_16x16x32_bf16(wa2, ba1, acc[2][1], 0, 0, 0);
        acc[2][2] = __builtin_amdgcn_mfma_f32_16x16x32_bf16(wa2, ba2, acc[2][2], 0, 0, 0);
        acc[2][3] = __builtin_amdgcn_mfma_f32_16x16x32_bf16(wa2, ba3, acc[2][3], 0, 0, 0);
        acc[3][0] = __builtin_amdgcn_mfma_f32_16x16x32_bf16(wa3, ba0, acc[3][0], 0, 0, 0);
        acc[3][1] = __builtin_amdgcn_mfma_f32_16x16x32_bf16(wa3, ba1, acc[3][1], 0, 0, 0);
        acc[3][2] = __builtin_amdgcn_mfma_f32_16x16x32_bf16(wa3, ba2, acc[3][2], 0, 0, 0);
        acc[3][3] = __builtin_amdgcn_mfma_f32_16x16x32_bf16(wa3, ba3, acc[3][3], 0, 0, 0);
        if (kk + 1 < KSTEPS) {           // rotate (pure SSA renames after unroll)
            wa0 = na0; wa1 = na1; wa2 = na2; wa3 = na3;
            ba0 = nb0; ba1 = nb1; ba2 = nb2; ba3 = nb3;
        }
    }

    __syncthreads();  // all waves done reading A (A may alias O)

#pragma unroll
    for (int ft = 0; ft < 4; ft++) {
        const f32x4 bv = *(const f32x4*)(bias + w * 64 + ft * 16 + qq * 4);
#pragma unroll
        for (int st = 0; st < 4; st++) {
            float v0 = acc[ft][st][0] + bv[0];
            float v1 = acc[ft][st][1] + bv[1];
            float v2 = acc[ft][st][2] + bv[2];
            float v3 = acc[ft][st][3] + bv[3];
            if (RELU) {
                v0 = fmaxf(v0, 0.0f); v1 = fmaxf(v1, 0.0f);
                v2 = fmaxf(v2, 0.0f); v3 = fmaxf(v3, 0.0f);
            }
            unsigned p0, p1;   // D.lo = bf16(S0), D.hi = bf16(S1) — RNE, matches f2bf
            asm("v_cvt_pk_bf16_f32 %0, %1, %2" : "=v"(p0) : "v"(v0), "v"(v1));
            asm("v_cvt_pk_bf16_f32 %0, %1, %2" : "=v"(p1) : "v"(v2), "v"(v3));
            uint2v pk; pk[0] = p0; pk[1] = p1;
            *(uint2v*)(O + (size_t)(st * 16 + col) * Os + w * 64 + ft * 16 + qq * 4) = pk;
        }
    }
    __syncthreads();  // O visible to next layer
}

// head (swapped): A-op = head weights Wt[16][256], B-op = acts of wave's 16 samples.
// Lane fragment = outputs qq*4..qq*4+3 of sample w*16+col -> float4 store for qq==0.
template <int NV, int OS>
__device__ __forceinline__ void head256(const short* A, int As,
                                        const short* __restrict__ Wt,
                                        const float* __restrict__ bias,
                                        float* Out, int tid)
{
    const int w = tid >> 6, lane = tid & 63, qq = lane >> 4, col = lane & 15;
    f32x4 acc = (f32x4)0.0f;
#pragma unroll
    for (int kk = 0; kk < 8; kk++) {
        short8 a = *(const short8*)(Wt + col * 256 + kk * 32 + qq * 8);
        short8 b = *(const short8*)(A + (size_t)(w * 16 + col) * As + kk * 32 + qq * 8);
        acc = __builtin_amdgcn_mfma_f32_16x16x32_bf16(a, b, acc, 0, 0, 0);
    }
    const int s = w * 16 + col;
    if (qq == 0) {
        f32x4 o;
#pragma unroll
        for (int i = 0; i < 4; i++) o[i] = acc[i] + bias[i];
        *(f32x4*)(Out + s * OS) = o;
    } else if (NV == 5 && qq == 1) {
        Out[s * OS + 4] = acc[0] + bias[4];
    }
}

__global__ __launch_bounds__(256, 3)
void nerf_mlp(const float* __restrict__ points, const float* __restrict__ dirsv,
              const float* __restrict__ timev, const short* __restrict__ wt,
              const float* __restrict__ sb0, const float* __restrict__ sb1,
              const float* __restrict__ sb2, const float* __restrict__ sb3,
              const float* __restrict__ sb4,
              const float* __restrict__ db0, const float* __restrict__ db1,
              const float* __restrict__ db2, const float* __restrict__ db3,
              const float* __restrict__ db4,
              float* __restrict__ o_sigma, float* __restrict__ o_r,
              float* __restrict__ o_g, float* __restrict__ o_b,
              float* __restrict__ o_bw)
{
    __shared__ short E[BM][ES];   // 17.0 KB: encoding, Kpad=128 (zeros for d>=99)
    __shared__ short Hb[BM][HS];  // 33.0 KB: activations, updated in-place
    __shared__ float so[BM][4];
    __shared__ float dn[BM][8];   // stride 8 so head can float4-store

    const int tid = threadIdx.x;
    const int m0  = blockIdx.x * BM;

    // ---- positional encoding -> E (bf16). Pair loop: one sincosf per (sin,cos). ----
    // torch order: [x, sin(f0 x)*3, cos(f0 x)*3, sin(f1 x)*3, ...]
    for (int idx = tid; idx < BM * 64; idx += 256) {
        const int s = idx >> 6, j = idx & 63, m = m0 + s;
        if (j < 46) {
            float x; int dsin, dcos;
            if (j < 30) {                       // pos: 10 bands x 3 coords
                const int l = j / 3, c = j - 3 * l;
                x = points[m * 3 + c] * (float)(1 << l);
                dsin = 3 + l * 6 + c; dcos = dsin + 3;
            } else if (j < 42) {                // dirs: 4 bands x 3 coords
                const int jj = j - 30, l = jj / 3, c = jj - 3 * l;
                x = dirsv[m * 3 + c] * (float)(1 << l);
                dsin = 66 + l * 6 + c; dcos = dsin + 3;
            } else {                            // time: 4 bands x 1
                const int l = j - 42;
                x = timev[m] * (float)(1 << l);
                dsin = 91 + 2 * l; dcos = dsin + 1;
            }
            float sn, cs;
            sincosf(x, &sn, &cs);
            E[s][dsin] = f2bf(sn);
            E[s][dcos] = f2bf(cs);
        } else {                                // passthroughs + zero pad, 2 slots/thread
            int t = (j - 46) * 2;
#pragma unroll
            for (int u = 0; u < 2; u++, t++) {
                float v = 0.0f; int d;
                if (t < 3)       { d = t;        v = points[m * 3 + t]; }
                else if (t < 6)  { d = 60 + t;   v = dirsv[m * 3 + t - 3]; }  // 63..65
                else if (t == 6) { d = 90;       v = timev[m]; }
                else             { d = 92 + t; }                              // 99..127 = 0
                E[s][d] = f2bf(v);
            }
        }
    }
    __syncthreads();

    // ---- static MLP ----
    layer256<4, true>(&E[0][0],  ES, wt + SW0, sb0, &Hb[0][0], HS, tid);
    layer256<8, true>(&Hb[0][0], HS, wt + SW1, sb1, &Hb[0][0], HS, tid);
    layer256<8, true>(&Hb[0][0], HS, wt + SW2, sb2, &Hb[0][0], HS, tid);
    layer256<8, true>(&Hb[0][0], HS, wt + SW3, sb3, &Hb[0][0], HS, tid);
    head256<4, 4>(&Hb[0][0], HS, wt + SW4, sb4, &so[0][0], tid);
    // (ordering: dynamic layer0's internal barrier sits between these head reads
    //  of Hb and its own Hb overwrite)

    // ---- dynamic MLP ----
    layer256<4, true>(&E[0][0],  ES, wt + DW0, db0, &Hb[0][0], HS, tid);
    layer256<8, true>(&Hb[0][0], HS, wt + DW1, db1, &Hb[0][0], HS, tid);
    layer256<8, true>(&Hb[0][0], HS, wt + DW2, db2, &Hb[0][0], HS, tid);
    layer256<8, true>(&Hb[0][0], HS, wt + DW3, db3, &Hb[0][0], HS, tid);
    head256<5, 8>(&Hb[0][0], HS, wt + DW4, db4, &dn[0][0], tid);
    __syncthreads();

    // ---- blend ----
    if (tid < BM) {
        const int s = tid, m = m0 + s;
        const float bw = sigm(dn[s][4]);
        const float sigma = (1.f - bw) * so[s][0] + bw * dn[s][0];
        const float r  = (1.f - bw) * sigm(so[s][1]) + bw * sigm(dn[s][1]);
        const float gg = (1.f - bw) * sigm(so[s][2]) + bw * sigm(dn[s][2]);
        const float bb = (1.f - bw) * sigm(so[s][3]) + bw * sigm(dn[s][3]);
        o_sigma[m] = sigma; o_r[m] = r; o_g[m] = gg; o_b[m] = bb; o_bw[m] = bw;
    }
}

// ---------------- compositing: one wave per ray, shuffle scan ----------------
__global__ __launch_bounds__(256)
void nerf_comp(const float* __restrict__ zv,
               const float* __restrict__ o_sigma, const float* __restrict__ o_r,
               const float* __restrict__ o_g, const float* __restrict__ o_b,
               const float* __restrict__ o_bw, float* __restrict__ out)
{
    const int ray  = blockIdx.x * 4 + (threadIdx.x >> 6);
    const int lane = threadIdx.x & 63;
    const int base = ray * SAMP;
    const int s0 = 2 * lane, s1 = s0 + 1;

    const float z0 = zv[base + s0];
    const float z1 = zv[base + s1];
    const float z2 = (lane < 63) ? zv[base + s1 + 1] : 0.0f;
    const float d0 = z1 - z0;
    const float d1 = (lane < 63) ? (z2 - z1) : 1e10f;

    const float sg0 = o_sigma[base + s0], sg1 = o_sigma[base + s1];
    const float a0 = 1.0f - expf(-sg0 * d0);
    const float a1 = 1.0f - expf(-sg1 * d1);
    const float f0 = 1.0f - a0 + 1e-10f;
    const float f1 = 1.0f - a1 + 1e-10f;

    // inclusive multiplicative scan of p = f0*f1 across lanes
    float incl = f0 * f1;
#pragma unroll
    for (int dlt = 1; dlt < 64; dlt <<= 1) {
        const float t = __shfl_up(incl, dlt);
        if (lane >= dlt) incl *= t;
    }
    float ex = __shfl_up(incl, 1);
    if (lane == 0) ex = 1.0f;

    const float t0 = ex;          // trans for s0
    const float t1 = ex * f0;     // trans for s1
    const float w0 = a0 * t0, w1 = a1 * t1;

    const float bw0 = o_bw[base + s0], bw1 = o_bw[base + s1];
    out[OUT_W  + base + s0] = w0;             out[OUT_W  + base + s1] = w1;
    out[OUT_SW + base + s0] = (1.f - bw0) * w0; out[OUT_SW + base + s1] = (1.f - bw1) * w1;
    out[OUT_DW + base + s0] = bw0 * w0;       out[OUT_DW + base + s1] = bw1 * w1;

    float pr = w0 * o_r[base + s0] + w1 * o_r[base + s1];
    float pg = w0 * o_g[base + s0] + w1 * o_g[base + s1];
    float pb = w0 * o_b[base + s0] + w1 * o_b[base + s1];
    float pd = w0 * z0 + w1 * z1;
#pragma unroll
    for (int dlt = 32; dlt >= 1; dlt >>= 1) {
        pr += __shfl_down(pr, dlt);
        pg += __shfl_down(pg, dlt);
        pb += __shfl_down(pb, dlt);
        pd += __shfl_down(pd, dlt);
    }
    if (lane == 0) {
        out[OUT_RGB + ray * 3 + 0] = pr;
        out[OUT_RGB + ray * 3 + 1] = pg;
        out[OUT_RGB + ray * 3 + 2] = pb;
        out[OUT_DEPTH + ray] = pd;
    }
}

extern "C" void kernel_launch(void* const* d_in, const int* in_sizes, int n_in,
                              void* d_out, int out_size, void* d_ws, size_t ws_size,
                              hipStream_t stream)
{
    const float* points = (const float*)d_in[0];
    const float* dirsv  = (const float*)d_in[1];
    const float* zvals  = (const float*)d_in[2];
    const float* timev  = (const float*)d_in[3];

    const float *sW[5], *sb[5], *dW[5], *db[5];
    if (in_sizes[6] == 99 * 256) {
        for (int i = 0; i < 5; i++) {   // interleaved (sW_i, sb_i, dW_i, db_i)
            sW[i] = (const float*)d_in[4 + 4 * i + 0];
            sb[i] = (const float*)d_in[4 + 4 * i + 1];
            dW[i] = (const float*)d_in[4 + 4 * i + 2];
            db[i] = (const float*)d_in[4 + 4 * i + 3];
        }
    } else {
        for (int i = 0; i < 5; i++) {   // all static then all dynamic
            sW[i] = (const float*)d_in[4 + 2 * i + 0];
            sb[i] = (const float*)d_in[4 + 2 * i + 1];
            dW[i] = (const float*)d_in[14 + 2 * i + 0];
            db[i] = (const float*)d_in[14 + 2 * i + 1];
        }
    }

    // ws layout: bf16 weights (933888 B) then 5 fp32 per-sample arrays (1 MB each)
    short* wt = (short*)d_ws;
    float* ws = (float*)((char*)d_ws + (size_t)WTOT * 2);
    float* o_sigma = ws;
    float* o_r  = ws + (size_t)MTOT * 1;
    float* o_g  = ws + (size_t)MTOT * 2;
    float* o_b  = ws + (size_t)MTOT * 3;
    float* o_bw = ws + (size_t)MTOT * 4;

    prep_weights<<<(WTOT + 255) / 256, 256, 0, stream>>>(
        sW[0], sW[1], sW[2], sW[3], sW[4], dW[0], dW[1], dW[2], dW[3], dW[4], wt);

    nerf_mlp<<<MTOT / BM, 256, 0, stream>>>(points, dirsv, timev, wt,
        sb[0], sb[1], sb[2], sb[3], sb[4], db[0], db[1], db[2], db[3], db[4],
        o_sigma, o_r, o_g, o_b, o_bw);

    nerf_comp<<<RAYS / 4, 256, 0, stream>>>(zvals, o_sigma, o_r, o_g, o_b, o_bw,
                                            (float*)d_out);
}

// Round 3
// 646.967 us; speedup vs baseline: 1.0761x; 1.0761x over previous
//
#include <hip/hip_runtime.h>
#include <math.h>

// FusionNeRF round 5:
//   - Round-4 post-mortem: counters identical to round 3 => (a) scratch was from
//     sincosf's address-taken output (108MB writes), not the prefetch arrays;
//     (b) compiler re-sank the prefetch loads (VGPR stuck 84) — dbuf deleted.
//   - This round: T4-style raw barriers (s_waitcnt lgkmcnt(0) only; vmcnt NEVER
//     drained at layer boundaries), cross-layer weight prefetch held in flight
//     through the barriers, sched_barrier(0)-pinned in-loop double buffer,
//     sinf/cosf (no sincosf scratch).

#define RAYS 2048
#define SAMP 128
#define MTOT (RAYS * SAMP)
#define HD   256
#define BM   64              // samples per block
#define ES   136             // enc LDS stride (bf16), Kpad=128 (+8 pad)
#define HS   264             // hidden LDS stride (bf16), 256 (+8 pad)

// output float offsets
#define OUT_RGB   0
#define OUT_DEPTH 6144
#define OUT_W     8192
#define OUT_SW    270336
#define OUT_DW    532480

// bf16 weight workspace offsets (elements)
#define SW0 0
#define SW1 32768
#define SW2 98304
#define SW3 163840
#define SW4 229376
#define DW0 233472
#define DW1 266240
#define DW2 331776
#define DW3 397312
#define DW4 462848
#define WTOT 466944

typedef __attribute__((ext_vector_type(8))) short short8;
typedef __attribute__((ext_vector_type(4))) float f32x4;
typedef __attribute__((ext_vector_type(2))) unsigned int uint2v;

__device__ __forceinline__ float sigm(float x) { return 1.0f / (1.0f + expf(-x)); }

__device__ __forceinline__ short f2bf(float f) {   // RNE fp32 -> bf16
    union { float f; unsigned u; } v; v.f = f;
    unsigned r = v.u + 0x7fffu + ((v.u >> 16) & 1u);
    return (short)(r >> 16);
}

// Raw barrier with LDS-visibility wait only: outstanding GLOBAL loads (vmcnt)
// stay in flight across the barrier (T4). sched_barrier(0) fences compiler
// motion on both sides (rule #18).
__device__ __forceinline__ void bar_lgkm() {
    asm volatile("s_waitcnt lgkmcnt(0)" ::: "memory");
    __builtin_amdgcn_sched_barrier(0);
    __builtin_amdgcn_s_barrier();
    __builtin_amdgcn_sched_barrier(0);
}
// Ordering-only barrier (no LDS writes pending; reads already consumed by MFMA).
__device__ __forceinline__ void bar_only() {
    __builtin_amdgcn_sched_barrier(0);
    __builtin_amdgcn_s_barrier();
    __builtin_amdgcn_sched_barrier(0);
}

// ---------------- weight prep: W[K][N] fp32 -> Wt[Npad][Kpad] bf16 ----------------
__device__ __forceinline__ void conv1(const float* __restrict__ src, short* __restrict__ dst,
                                      int local, int K, int N, int Kpad) {
    const int n = local / Kpad, k = local - n * Kpad;
    const float v = (k < K && n < N) ? src[k * N + n] : 0.0f;
    dst[local] = f2bf(v);
}

__global__ __launch_bounds__(256)
void prep_weights(const float* sW0, const float* sW1, const float* sW2,
                  const float* sW3, const float* sW4,
                  const float* dW0, const float* dW1, const float* dW2,
                  const float* dW3, const float* dW4, short* __restrict__ dst)
{
    const int idx = blockIdx.x * 256 + threadIdx.x;
    if (idx >= WTOT) return;
    if      (idx < SW1) conv1(sW0, dst + SW0, idx - SW0,  90, 256, 128);
    else if (idx < SW2) conv1(sW1, dst + SW1, idx - SW1, 256, 256, 256);
    else if (idx < SW3) conv1(sW2, dst + SW2, idx - SW2, 256, 256, 256);
    else if (idx < SW4) conv1(sW3, dst + SW3, idx - SW3, 256, 256, 256);
    else if (idx < DW0) conv1(sW4, dst + SW4, idx - SW4, 256,   4, 256);
    else if (idx < DW1) conv1(dW0, dst + DW0, idx - DW0,  99, 256, 128);
    else if (idx < DW2) conv1(dW1, dst + DW1, idx - DW1, 256, 256, 256);
    else if (idx < DW3) conv1(dW2, dst + DW2, idx - DW2, 256, 256, 256);
    else if (idx < DW4) conv1(dW3, dst + DW3, idx - DW3, 256, 256, 256);
    else                conv1(dW4, dst + DW4, idx - DW4, 256,   5, 256);
}

// 4 weight fragments (kk=0 k-slice) for one wave's 64-feature tile.
struct WF { short8 a0, a1, a2, a3; };

__device__ __forceinline__ WF load_wf(const short* __restrict__ Wt, int K, int tid) {
    const int w = tid >> 6, lane = tid & 63, qq = lane >> 4, col = lane & 15;
    const short* base = Wt + (size_t)(w * 64 + col) * K + qq * 8;
    WF f;
    f.a0 = *(const short8*)(base + (size_t)0 * 16 * K);
    f.a1 = *(const short8*)(base + (size_t)1 * 16 * K);
    f.a2 = *(const short8*)(base + (size_t)2 * 16 * K);
    f.a3 = *(const short8*)(base + (size_t)3 * 16 * K);
    return f;
}

// ---------------- MFMA dense layer (swapped operands, pinned pipeline) ----------
// A-operand = weights Wt[256][K] (global), B-operand = acts [64][K] (LDS).
// cw = preloaded kk=0 weight frags (issued before the previous barrier -> in
// flight across it). Returns the NEXT layer's kk=0 frags, issued before barrier1
// so they fly through barrier+epilogue+barrier.
template <int KSTEPS, bool RELU>
__device__ __forceinline__ WF layer256(const short* A, int As,
                                       const short* __restrict__ Wt, WF cw,
                                       const short* __restrict__ nWt, int nK,
                                       const float* __restrict__ bias,
                                       short* O, int Os, int tid)
{
    const int w = tid >> 6, lane = tid & 63, qq = lane >> 4, col = lane & 15;
    const int K = KSTEPS * 32;

    f32x4 acc[4][4];   // acc[ft][st] — const-indexed only
#pragma unroll
    for (int ft = 0; ft < 4; ft++)
#pragma unroll
        for (int st = 0; st < 4; st++) acc[ft][st] = (f32x4)0.0f;

    const short* wbase = Wt + (size_t)(w * 64 + col) * K + qq * 8;
    const short* abase = A + (size_t)col * As + qq * 8;

    short8 wa0 = cw.a0, wa1 = cw.a1, wa2 = cw.a2, wa3 = cw.a3;
    short8 ba0 = *(const short8*)(abase + 0 * 16 * As);
    short8 ba1 = *(const short8*)(abase + 1 * 16 * As);
    short8 ba2 = *(const short8*)(abase + 2 * 16 * As);
    short8 ba3 = *(const short8*)(abase + 3 * 16 * As);

#pragma unroll
    for (int kk = 0; kk < KSTEPS; kk++) {
        short8 na0, na1, na2, na3, nb0, nb1, nb2, nb3;
        if (kk + 1 < KSTEPS) {           // prefetch kk+1 while MFMA consumes kk
            const int ko = (kk + 1) * 32;
            na0 = *(const short8*)(wbase + (size_t)0 * 16 * K + ko);
            na1 = *(const short8*)(wbase + (size_t)1 * 16 * K + ko);
            na2 = *(const short8*)(wbase + (size_t)2 * 16 * K + ko);
            na3 = *(const short8*)(wbase + (size_t)3 * 16 * K + ko);
            nb0 = *(const short8*)(abase + 0 * 16 * As + ko);
            nb1 = *(const short8*)(abase + 1 * 16 * As + ko);
            nb2 = *(const short8*)(abase + 2 * 16 * As + ko);
            nb3 = *(const short8*)(abase + 3 * 16 * As + ko);
        }
        __builtin_amdgcn_sched_barrier(0);  // pin: loads above, MFMAs below
        acc[0][0] = __builtin_amdgcn_mfma_f32_16x16x32_bf16(wa0, ba0, acc[0][0], 0, 0, 0);
        acc[0][1] = __builtin_amdgcn_mfma_f32_16x16x32_bf16(wa0, ba1, acc[0][1], 0, 0, 0);
        acc[0][2] = __builtin_amdgcn_mfma_f32_16x16x32_bf16(wa0, ba2, acc[0][2], 0, 0, 0);
        acc[0][3] = __builtin_amdgcn_mfma_f32_16x16x32_bf16(wa0, ba3, acc[0][3], 0, 0, 0);
        acc[1][0] = __builtin_amdgcn_mfma_f32_16x16x32_bf16(wa1, ba0, acc[1][0], 0, 0, 0);
        acc[1][1] = __builtin_amdgcn_mfma_f32_16x16x32_bf16(wa1, ba1, acc[1][1], 0, 0, 0);
        acc[1][2] = __builtin_amdgcn_mfma_f32_16x16x32_bf16(wa1, ba2, acc[1][2], 0, 0, 0);
        acc[1][3] = __builtin_amdgcn_mfma_f32_16x16x32_bf16(wa1, ba3, acc[1][3], 0, 0, 0);
        acc[2][0] = __builtin_amdgcn_mfma_f32_16x16x32_bf16(wa2, ba0, acc[2][0], 0, 0, 0);
        acc[2][1] = __builtin_amdgcn_mfma_f32_16x16x32_bf16(wa2, ba1, acc[2][1], 0, 0, 0);
        acc[2][2] = __builtin_amdgcn_mfma_f32_16x16x32_bf16(wa2, ba2, acc[2][2], 0, 0, 0);
        acc[2][3] = __builtin_amdgcn_mfma_f32_16x16x32_bf16(wa2, ba3, acc[2][3], 0, 0, 0);
        acc[3][0] = __builtin_amdgcn_mfma_f32_16x16x32_bf16(wa3, ba0, acc[3][0], 0, 0, 0);
        acc[3][1] = __builtin_amdgcn_mfma_f32_16x16x32_bf16(wa3, ba1, acc[3][1], 0, 0, 0);
        acc[3][2] = __builtin_amdgcn_mfma_f32_16x16x32_bf16(wa3, ba2, acc[3][2], 0, 0, 0);
        acc[3][3] = __builtin_amdgcn_mfma_f32_16x16x32_bf16(wa3, ba3, acc[3][3], 0, 0, 0);
        if (kk + 1 < KSTEPS) {           // rotate (SSA renames after full unroll)
            wa0 = na0; wa1 = na1; wa2 = na2; wa3 = na3;
            ba0 = nb0; ba1 = nb1; ba2 = nb2; ba3 = nb3;
        }
    }

    // Prefetch NEXT layer's kk=0 weight frags: issued before barrier1, waited by
    // dataflow at the next layer's first MFMA (vmcnt not drained at barriers).
    WF nf = load_wf(nWt, nK, tid);

    bar_only();   // all waves done reading A (A may alias O); no LDS writes pending

#pragma unroll
    for (int ft = 0; ft < 4; ft++) {
        const f32x4 bv = *(const f32x4*)(bias + w * 64 + ft * 16 + qq * 4);
#pragma unroll
        for (int st = 0; st < 4; st++) {
            float v0 = acc[ft][st][0] + bv[0];
            float v1 = acc[ft][st][1] + bv[1];
            float v2 = acc[ft][st][2] + bv[2];
            float v3 = acc[ft][st][3] + bv[3];
            if (RELU) {
                v0 = fmaxf(v0, 0.0f); v1 = fmaxf(v1, 0.0f);
                v2 = fmaxf(v2, 0.0f); v3 = fmaxf(v3, 0.0f);
            }
            unsigned p0, p1;   // D.lo = bf16(S0), D.hi = bf16(S1) — RNE, matches f2bf
            asm("v_cvt_pk_bf16_f32 %0, %1, %2" : "=v"(p0) : "v"(v0), "v"(v1));
            asm("v_cvt_pk_bf16_f32 %0, %1, %2" : "=v"(p1) : "v"(v2), "v"(v3));
            uint2v pk; pk[0] = p0; pk[1] = p1;
            *(uint2v*)(O + (size_t)(st * 16 + col) * Os + w * 64 + ft * 16 + qq * 4) = pk;
        }
    }
    bar_lgkm();   // O visible to next layer (lgkm drain only; vmcnt stays counted)
    return nf;
}

// head (swapped): A-op = head weights Wt[16][256], B-op = acts of wave's 16 samples.
template <int NV, int OS>
__device__ __forceinline__ void head256(const short* A, int As,
                                        const short* __restrict__ Wt,
                                        const float* __restrict__ bias,
                                        float* Out, int tid)
{
    const int w = tid >> 6, lane = tid & 63, qq = lane >> 4, col = lane & 15;
    f32x4 acc = (f32x4)0.0f;
#pragma unroll
    for (int kk = 0; kk < 8; kk++) {
        short8 a = *(const short8*)(Wt + col * 256 + kk * 32 + qq * 8);
        short8 b = *(const short8*)(A + (size_t)(w * 16 + col) * As + kk * 32 + qq * 8);
        acc = __builtin_amdgcn_mfma_f32_16x16x32_bf16(a, b, acc, 0, 0, 0);
    }
    const int s = w * 16 + col;
    if (qq == 0) {
        f32x4 o;
#pragma unroll
        for (int i = 0; i < 4; i++) o[i] = acc[i] + bias[i];
        *(f32x4*)(Out + s * OS) = o;
    } else if (NV == 5 && qq == 1) {
        Out[s * OS + 4] = acc[0] + bias[4];
    }
}

__global__ __launch_bounds__(256, 3)
void nerf_mlp(const float* __restrict__ points, const float* __restrict__ dirsv,
              const float* __restrict__ timev, const short* __restrict__ wt,
              const float* __restrict__ sb0, const float* __restrict__ sb1,
              const float* __restrict__ sb2, const float* __restrict__ sb3,
              const float* __restrict__ sb4,
              const float* __restrict__ db0, const float* __restrict__ db1,
              const float* __restrict__ db2, const float* __restrict__ db3,
              const float* __restrict__ db4,
              float* __restrict__ o_sigma, float* __restrict__ o_r,
              float* __restrict__ o_g, float* __restrict__ o_b,
              float* __restrict__ o_bw)
{
    __shared__ short E[BM][ES];   // 17.0 KB: encoding, Kpad=128 (zeros for d>=99)
    __shared__ short Hb[BM][HS];  // 33.0 KB: activations, updated in-place
    __shared__ float so[BM][4];
    __shared__ float dn[BM][8];   // stride 8 so head can float4-store

    const int tid = threadIdx.x;
    const int m0  = blockIdx.x * BM;

    // Static layer-0 weight frags: issued first, fully hidden under encoding.
    WF f = load_wf(wt + SW0, 128, tid);

    // ---- positional encoding -> E (bf16). Paired indexing, separate sinf/cosf
    //      (sincosf's address-taken output forced scratch: 108MB writeback, r3/r4). ----
    for (int idx = tid; idx < BM * 64; idx += 256) {
        const int s = idx >> 6, j = idx & 63, m = m0 + s;
        if (j < 46) {
            float x; int dsin, dcos;
            if (j < 30) {                       // pos: 10 bands x 3 coords
                const int l = j / 3, c = j - 3 * l;
                x = points[m * 3 + c] * (float)(1 << l);
                dsin = 3 + l * 6 + c; dcos = dsin + 3;
            } else if (j < 42) {                // dirs: 4 bands x 3 coords
                const int jj = j - 30, l = jj / 3, c = jj - 3 * l;
                x = dirsv[m * 3 + c] * (float)(1 << l);
                dsin = 66 + l * 6 + c; dcos = dsin + 3;
            } else {                            // time: 4 bands x 1
                const int l = j - 42;
                x = timev[m] * (float)(1 << l);
                dsin = 91 + 2 * l; dcos = dsin + 1;
            }
            E[s][dsin] = f2bf(sinf(x));
            E[s][dcos] = f2bf(cosf(x));
        } else {                                // passthroughs + zero pad, 2 slots/thread
            int t = (j - 46) * 2;
#pragma unroll
            for (int u = 0; u < 2; u++, t++) {
                float v = 0.0f; int d;
                if (t < 3)       { d = t;        v = points[m * 3 + t]; }
                else if (t < 6)  { d = 60 + t;   v = dirsv[m * 3 + t - 3]; }  // 63..65
                else if (t == 6) { d = 90;       v = timev[m]; }
                else             { d = 92 + t; }                              // 99..127 = 0
                E[s][d] = f2bf(v);
            }
        }
    }
    bar_lgkm();

    // ---- static MLP (each layer prefetches the next layer's kk=0 weight frags) ----
    f = layer256<4, true>(&E[0][0],  ES, wt + SW0, f, wt + SW1, 256, sb0, &Hb[0][0], HS, tid);
    f = layer256<8, true>(&Hb[0][0], HS, wt + SW1, f, wt + SW2, 256, sb1, &Hb[0][0], HS, tid);
    f = layer256<8, true>(&Hb[0][0], HS, wt + SW2, f, wt + SW3, 256, sb2, &Hb[0][0], HS, tid);
    // static L3 prefetches DYNAMIC L0's frags (live across the static head):
    f = layer256<8, true>(&Hb[0][0], HS, wt + SW3, f, wt + DW0, 128, sb3, &Hb[0][0], HS, tid);
    head256<4, 4>(&Hb[0][0], HS, wt + SW4, sb4, &so[0][0], tid);
    // (dynamic L0's barrier1 orders these head reads of Hb vs its Hb overwrite)

    // ---- dynamic MLP ----
    f = layer256<4, true>(&E[0][0],  ES, wt + DW0, f, wt + DW1, 256, db0, &Hb[0][0], HS, tid);
    f = layer256<8, true>(&Hb[0][0], HS, wt + DW1, f, wt + DW2, 256, db1, &Hb[0][0], HS, tid);
    f = layer256<8, true>(&Hb[0][0], HS, wt + DW2, f, wt + DW3, 256, db2, &Hb[0][0], HS, tid);
    // last layer: dummy prefetch target (unused result -> DCE'd, always in-bounds)
    f = layer256<8, true>(&Hb[0][0], HS, wt + DW3, f, wt + SW0, 128, db3, &Hb[0][0], HS, tid);
    head256<5, 8>(&Hb[0][0], HS, wt + DW4, db4, &dn[0][0], tid);
    bar_lgkm();

    // ---- blend ----
    if (tid < BM) {
        const int s = tid, m = m0 + s;
        const float bw = sigm(dn[s][4]);
        const float sigma = (1.f - bw) * so[s][0] + bw * dn[s][0];
        const float r  = (1.f - bw) * sigm(so[s][1]) + bw * sigm(dn[s][1]);
        const float gg = (1.f - bw) * sigm(so[s][2]) + bw * sigm(dn[s][2]);
        const float bb = (1.f - bw) * sigm(so[s][3]) + bw * sigm(dn[s][3]);
        o_sigma[m] = sigma; o_r[m] = r; o_g[m] = gg; o_b[m] = bb; o_bw[m] = bw;
    }
}

// ---------------- compositing: one wave per ray, shuffle scan ----------------
__global__ __launch_bounds__(256)
void nerf_comp(const float* __restrict__ zv,
               const float* __restrict__ o_sigma, const float* __restrict__ o_r,
               const float* __restrict__ o_g, const float* __restrict__ o_b,
               const float* __restrict__ o_bw, float* __restrict__ out)
{
    const int ray  = blockIdx.x * 4 + (threadIdx.x >> 6);
    const int lane = threadIdx.x & 63;
    const int base = ray * SAMP;
    const int s0 = 2 * lane, s1 = s0 + 1;

    const float z0 = zv[base + s0];
    const float z1 = zv[base + s1];
    const float z2 = (lane < 63) ? zv[base + s1 + 1] : 0.0f;
    const float d0 = z1 - z0;
    const float d1 = (lane < 63) ? (z2 - z1) : 1e10f;

    const float sg0 = o_sigma[base + s0], sg1 = o_sigma[base + s1];
    const float a0 = 1.0f - expf(-sg0 * d0);
    const float a1 = 1.0f - expf(-sg1 * d1);
    const float f0 = 1.0f - a0 + 1e-10f;
    const float f1 = 1.0f - a1 + 1e-10f;

    // inclusive multiplicative scan of p = f0*f1 across lanes
    float incl = f0 * f1;
#pragma unroll
    for (int dlt = 1; dlt < 64; dlt <<= 1) {
        const float t = __shfl_up(incl, dlt);
        if (lane >= dlt) incl *= t;
    }
    float ex = __shfl_up(incl, 1);
    if (lane == 0) ex = 1.0f;

    const float t0 = ex;          // trans for s0
    const float t1 = ex * f0;     // trans for s1
    const float w0 = a0 * t0, w1 = a1 * t1;

    const float bw0 = o_bw[base + s0], bw1 = o_bw[base + s1];
    out[OUT_W  + base + s0] = w0;             out[OUT_W  + base + s1] = w1;
    out[OUT_SW + base + s0] = (1.f - bw0) * w0; out[OUT_SW + base + s1] = (1.f - bw1) * w1;
    out[OUT_DW + base + s0] = bw0 * w0;       out[OUT_DW + base + s1] = bw1 * w1;

    float pr = w0 * o_r[base + s0] + w1 * o_r[base + s1];
    float pg = w0 * o_g[base + s0] + w1 * o_g[base + s1];
    float pb = w0 * o_b[base + s0] + w1 * o_b[base + s1];
    float pd = w0 * z0 + w1 * z1;
#pragma unroll
    for (int dlt = 32; dlt >= 1; dlt >>= 1) {
        pr += __shfl_down(pr, dlt);
        pg += __shfl_down(pg, dlt);
        pb += __shfl_down(pb, dlt);
        pd += __shfl_down(pd, dlt);
    }
    if (lane == 0) {
        out[OUT_RGB + ray * 3 + 0] = pr;
        out[OUT_RGB + ray * 3 + 1] = pg;
        out[OUT_RGB + ray * 3 + 2] = pb;
        out[OUT_DEPTH + ray] = pd;
    }
}

extern "C" void kernel_launch(void* const* d_in, const int* in_sizes, int n_in,
                              void* d_out, int out_size, void* d_ws, size_t ws_size,
                              hipStream_t stream)
{
    const float* points = (const float*)d_in[0];
    const float* dirsv  = (const float*)d_in[1];
    const float* zvals  = (const float*)d_in[2];
    const float* timev  = (const float*)d_in[3];

    const float *sW[5], *sb[5], *dW[5], *db[5];
    if (in_sizes[6] == 99 * 256) {
        for (int i = 0; i < 5; i++) {   // interleaved (sW_i, sb_i, dW_i, db_i)
            sW[i] = (const float*)d_in[4 + 4 * i + 0];
            sb[i] = (const float*)d_in[4 + 4 * i + 1];
            dW[i] = (const float*)d_in[4 + 4 * i + 2];
            db[i] = (const float*)d_in[4 + 4 * i + 3];
        }
    } else {
        for (int i = 0; i < 5; i++) {   // all static then all dynamic
            sW[i] = (const float*)d_in[4 + 2 * i + 0];
            sb[i] = (const float*)d_in[4 + 2 * i + 1];
            dW[i] = (const float*)d_in[14 + 2 * i + 0];
            db[i] = (const float*)d_in[14 + 2 * i + 1];
        }
    }

    // ws layout: bf16 weights (933888 B) then 5 fp32 per-sample arrays (1 MB each)
    short* wt = (short*)d_ws;
    float* ws = (float*)((char*)d_ws + (size_t)WTOT * 2);
    float* o_sigma = ws;
    float* o_r  = ws + (size_t)MTOT * 1;
    float* o_g  = ws + (size_t)MTOT * 2;
    float* o_b  = ws + (size_t)MTOT * 3;
    float* o_bw = ws + (size_t)MTOT * 4;

    prep_weights<<<(WTOT + 255) / 256, 256, 0, stream>>>(
        sW[0], sW[1], sW[2], sW[3], sW[4], dW[0], dW[1], dW[2], dW[3], dW[4], wt);

    nerf_mlp<<<MTOT / BM, 256, 0, stream>>>(points, dirsv, timev, wt,
        sb[0], sb[1], sb[2], sb[3], sb[4], db[0], db[1], db[2], db[3], db[4],
        o_sigma, o_r, o_g, o_b, o_bw);

    nerf_comp<<<RAYS / 4, 256, 0, stream>>>(zvals, o_sigma, o_r, o_g, o_b, o_bw,
                                            (float*)d_out);
}

// Round 6
// 614.194 us; speedup vs baseline: 1.1336x; 1.0534x over previous
//
#include <hip/hip_runtime.h>
#include <math.h>

// FusionNeRF round 8:
//   - r7 post-mortem: (1) dummy nf prefetch left in-flight asm loads whose dest
//     VGPRs the compiler reallocated (value dead) -> retire-time clobber ->
//     replay-varying error. (2) bias-init of acc changed fp32 rounding order ->
//     absmax 0.0156->0.0625. Both r7-specific.
//   - r8: validated r5 skeleton + (a) LDS 53504 B -> 3 blocks/CU; (b) asm
//     in-loop k-pipeline, SELF-CONTAINED per layer (no load crosses a plain-C
//     region or barrier; last k-step drains vmcnt(0) lgkmcnt(0)); (c) bias in
//     epilogue (r5 numerics).

#define RAYS 2048
#define SAMP 128
#define MTOT (RAYS * SAMP)
#define HD   256
#define BM   64              // samples per block
#define ES   136             // enc LDS stride (bf16), Kpad=128 (+8 pad, 272B rows)
#define HS   264             // hidden LDS stride (bf16), 256 (+8 pad, 528B rows)

// output float offsets
#define OUT_RGB   0
#define OUT_DEPTH 6144
#define OUT_W     8192
#define OUT_SW    270336
#define OUT_DW    532480

// bf16 weight workspace offsets (elements)
#define SW0 0
#define SW1 32768
#define SW2 98304
#define SW3 163840
#define SW4 229376
#define DW0 233472
#define DW1 266240
#define DW2 331776
#define DW3 397312
#define DW4 462848
#define WTOT 466944

typedef __attribute__((ext_vector_type(8))) short short8;
typedef __attribute__((ext_vector_type(4))) float f32x4;
typedef __attribute__((ext_vector_type(2))) unsigned int uint2v;

__device__ __forceinline__ float sigm(float x) { return 1.0f / (1.0f + expf(-x)); }

__device__ __forceinline__ short f2bf(float f) {   // RNE fp32 -> bf16
    union { float f; unsigned u; } v; v.f = f;
    unsigned r = v.u + 0x7fffu + ((v.u >> 16) & 1u);
    return (short)(r >> 16);
}

// Unmovable memory ops (volatile asm). Counted waits + sched_barrier(0) (rule #18).
#define GLB_LOAD(dst, ptr, imm) \
    asm volatile("global_load_dwordx4 %0, %1, off offset:%c2" \
                 : "=v"(dst) : "v"(ptr), "n"(imm))
#define LDS_READ(dst, addr, imm) \
    asm volatile("ds_read_b128 %0, %1 offset:%c2" \
                 : "=v"(dst) : "v"(addr), "n"(imm))
#define WAITCNT(vm, lg) do { \
    asm volatile("s_waitcnt vmcnt(%c0) lgkmcnt(%c1)" :: "n"(vm), "n"(lg)); \
    __builtin_amdgcn_sched_barrier(0); } while (0)

// Barrier with LDS drain only (validated in r5's 592us run).
__device__ __forceinline__ void bar_lgkm() {
    __builtin_amdgcn_sched_barrier(0);
    asm volatile("s_waitcnt lgkmcnt(0)\n\ts_barrier" ::: "memory");
    __builtin_amdgcn_sched_barrier(0);
}
// Ordering-only barrier (all reads already drained via counted waits).
__device__ __forceinline__ void bar_only() {
    __builtin_amdgcn_sched_barrier(0);
    asm volatile("s_barrier" ::: "memory");
    __builtin_amdgcn_sched_barrier(0);
}

// ---------------- weight prep: W[K][N] fp32 -> Wt[Npad][Kpad] bf16 ----------------
__device__ __forceinline__ void conv1(const float* __restrict__ src, short* __restrict__ dst,
                                      int local, int K, int N, int Kpad) {
    const int n = local / Kpad, k = local - n * Kpad;
    const float v = (k < K && n < N) ? src[k * N + n] : 0.0f;
    dst[local] = f2bf(v);
}

__global__ __launch_bounds__(256)
void prep_weights(const float* sW0, const float* sW1, const float* sW2,
                  const float* sW3, const float* sW4,
                  const float* dW0, const float* dW1, const float* dW2,
                  const float* dW3, const float* dW4, short* __restrict__ dst)
{
    const int idx = blockIdx.x * 256 + threadIdx.x;
    if (idx >= WTOT) return;
    if      (idx < SW1) conv1(sW0, dst + SW0, idx - SW0,  90, 256, 128);
    else if (idx < SW2) conv1(sW1, dst + SW1, idx - SW1, 256, 256, 256);
    else if (idx < SW3) conv1(sW2, dst + SW2, idx - SW2, 256, 256, 256);
    else if (idx < SW4) conv1(sW3, dst + SW3, idx - SW3, 256, 256, 256);
    else if (idx < DW0) conv1(sW4, dst + SW4, idx - SW4, 256,   4, 256);
    else if (idx < DW1) conv1(dW0, dst + DW0, idx - DW0,  99, 256, 128);
    else if (idx < DW2) conv1(dW1, dst + DW1, idx - DW1, 256, 256, 256);
    else if (idx < DW3) conv1(dW2, dst + DW2, idx - DW2, 256, 256, 256);
    else if (idx < DW4) conv1(dW3, dst + DW3, idx - DW3, 256, 256, 256);
    else                conv1(dW4, dst + DW4, idx - DW4, 256,   5, 256);
}

// ---------------- MFMA dense layer: self-contained asm k-pipeline ---------------
// A-operand = weights Wt[256][K] (global, L2-hot), B-operand = acts [64][AS] (LDS).
// Entry: issue k0+k1 weights (GLB) + k0+k1 acts (LDS), wait (4,4).
// Steady: issue kk+1 (4 GLB + 4 LDS), wait (4,4). Last: wait (0,0) — ALL our
// vm/lgkm ops drained inside the layer; nothing in flight crosses plain-C code.
template <int KSTEPS, bool RELU, int AS>
__device__ __forceinline__ void layer256(const short* A,
                                         const short* __restrict__ Wt,
                                         const float* __restrict__ bias,
                                         short* O, int Os, int tid)
{
    const int w = tid >> 6, lane = tid & 63, qq = lane >> 4, col = lane & 15;
    constexpr int K = KSTEPS * 32;

    const short* wp0 = Wt + (size_t)(w * 64 +  0 + col) * K + qq * 8;
    const short* wp1 = Wt + (size_t)(w * 64 + 16 + col) * K + qq * 8;
    const short* wp2 = Wt + (size_t)(w * 64 + 32 + col) * K + qq * 8;
    const short* wp3 = Wt + (size_t)(w * 64 + 48 + col) * K + qq * 8;
    // LDS byte address (generic shared addr: low 32 bits are the LDS offset —
    // validated on-device in r7)
    const unsigned ab = (unsigned)(size_t)(const void*)A + (unsigned)((col * AS + qq * 8) * 2);

    short8 wa[2][4], ba[2][4];   // ping-pong, all indices compile-time after unroll

    // entry: k0 + k1 weights first (longest latency), then k0 + k1 acts
    GLB_LOAD(wa[0][0], wp0, 0);
    GLB_LOAD(wa[0][1], wp1, 0);
    GLB_LOAD(wa[0][2], wp2, 0);
    GLB_LOAD(wa[0][3], wp3, 0);
    GLB_LOAD(wa[1][0], wp0, 64);
    GLB_LOAD(wa[1][1], wp1, 64);
    GLB_LOAD(wa[1][2], wp2, 64);
    GLB_LOAD(wa[1][3], wp3, 64);
    LDS_READ(ba[0][0], ab, (0 * 16 * AS) * 2);
    LDS_READ(ba[0][1], ab, (1 * 16 * AS) * 2);
    LDS_READ(ba[0][2], ab, (2 * 16 * AS) * 2);
    LDS_READ(ba[0][3], ab, (3 * 16 * AS) * 2);
    LDS_READ(ba[1][0], ab, (0 * 16 * AS) * 2 + 64);
    LDS_READ(ba[1][1], ab, (1 * 16 * AS) * 2 + 64);
    LDS_READ(ba[1][2], ab, (2 * 16 * AS) * 2 + 64);
    LDS_READ(ba[1][3], ab, (3 * 16 * AS) * 2 + 64);
    WAITCNT(4, 4);   // k0 weights+acts ready; k1 in flight

    f32x4 acc[4][4];
#pragma unroll
    for (int ft = 0; ft < 4; ft++)
#pragma unroll
        for (int st = 0; st < 4; st++) acc[ft][st] = (f32x4)0.0f;

#pragma unroll
    for (int kk = 0; kk < KSTEPS; kk++) {
        const int c = kk & 1, nx = c ^ 1;
        if (kk > 0 && kk < KSTEPS - 1) {
            GLB_LOAD(wa[nx][0], wp0, (kk + 1) * 64);
            GLB_LOAD(wa[nx][1], wp1, (kk + 1) * 64);
            GLB_LOAD(wa[nx][2], wp2, (kk + 1) * 64);
            GLB_LOAD(wa[nx][3], wp3, (kk + 1) * 64);
            LDS_READ(ba[nx][0], ab, (0 * 16 * AS) * 2 + (kk + 1) * 64);
            LDS_READ(ba[nx][1], ab, (1 * 16 * AS) * 2 + (kk + 1) * 64);
            LDS_READ(ba[nx][2], ab, (2 * 16 * AS) * 2 + (kk + 1) * 64);
            LDS_READ(ba[nx][3], ab, (3 * 16 * AS) * 2 + (kk + 1) * 64);
            WAITCNT(4, 4);                 // wa[kk]/ba[kk] ready; kk+1 in flight
        } else if (kk == KSTEPS - 1) {
            WAITCNT(0, 0);                 // drain everything: layer self-contained
        }
#pragma unroll
        for (int ft = 0; ft < 4; ft++)
#pragma unroll
            for (int st = 0; st < 4; st++)
                acc[ft][st] = __builtin_amdgcn_mfma_f32_16x16x32_bf16(
                    wa[c][ft], ba[c][st], acc[ft][st], 0, 0, 0);
    }

    bar_only();       // all waves done reading A (A may alias O)

#pragma unroll
    for (int ft = 0; ft < 4; ft++) {
        const f32x4 bv = *(const f32x4*)(bias + w * 64 + ft * 16 + qq * 4);
#pragma unroll
        for (int st = 0; st < 4; st++) {
            float v0 = acc[ft][st][0] + bv[0];
            float v1 = acc[ft][st][1] + bv[1];
            float v2 = acc[ft][st][2] + bv[2];
            float v3 = acc[ft][st][3] + bv[3];
            if (RELU) {
                v0 = fmaxf(v0, 0.0f); v1 = fmaxf(v1, 0.0f);
                v2 = fmaxf(v2, 0.0f); v3 = fmaxf(v3, 0.0f);
            }
            unsigned p0, p1;   // RNE pack, matches f2bf
            asm("v_cvt_pk_bf16_f32 %0, %1, %2" : "=v"(p0) : "v"(v0), "v"(v1));
            asm("v_cvt_pk_bf16_f32 %0, %1, %2" : "=v"(p1) : "v"(v2), "v"(v3));
            uint2v pk; pk[0] = p0; pk[1] = p1;
            *(uint2v*)(O + (size_t)(st * 16 + col) * Os + w * 64 + ft * 16 + qq * 4) = pk;
        }
    }
    bar_lgkm();   // O visible to next layer
}

// head (swapped): A-op = head weights Wt[16][256], B-op = acts of wave's 16 samples.
// Plain C — at entry our asm vm/lgkm queues are EMPTY (layers drain), so the
// compiler's own waitcnt accounting is exact.
template <int NV, int OS>
__device__ __forceinline__ void head256(const short* A, int As,
                                        const short* __restrict__ Wt,
                                        const float* __restrict__ bias,
                                        float* Out, int tid)
{
    const int w = tid >> 6, lane = tid & 63, qq = lane >> 4, col = lane & 15;
    f32x4 acc = (f32x4)0.0f;
#pragma unroll
    for (int kk = 0; kk < 8; kk++) {
        short8 a = *(const short8*)(Wt + col * 256 + kk * 32 + qq * 8);
        short8 b = *(const short8*)(A + (size_t)(w * 16 + col) * As + kk * 32 + qq * 8);
        acc = __builtin_amdgcn_mfma_f32_16x16x32_bf16(a, b, acc, 0, 0, 0);
    }
    const int s = w * 16 + col;
    if (qq == 0) {
#pragma unroll
        for (int i = 0; i < 4; i++) Out[s * OS + i] = acc[i] + bias[i];
    } else if (NV == 5 && qq == 1) {
        Out[s * OS + 4] = acc[0] + bias[4];
    }
}

__global__ __launch_bounds__(256, 3)
void nerf_mlp(const float* __restrict__ points, const float* __restrict__ dirsv,
              const float* __restrict__ timev, const short* __restrict__ wt,
              const float* __restrict__ sb0, const float* __restrict__ sb1,
              const float* __restrict__ sb2, const float* __restrict__ sb3,
              const float* __restrict__ sb4,
              const float* __restrict__ db0, const float* __restrict__ db1,
              const float* __restrict__ db2, const float* __restrict__ db3,
              const float* __restrict__ db4,
              float* __restrict__ o_sigma, float* __restrict__ o_r,
              float* __restrict__ o_g, float* __restrict__ o_b,
              float* __restrict__ o_bw)
{
    __shared__ __align__(16) short E[BM][ES];   // 17408 B
    __shared__ __align__(16) short Hb[BM][HS];  // 33792 B
    __shared__ float so[BM][4];                 //  1024 B
    __shared__ float dn[BM][5];                 //  1280 B -> 53504 B => 3 blocks/CU

    const int tid = threadIdx.x;
    const int m0  = blockIdx.x * BM;

    // ---- positional encoding -> E (bf16). sinf/cosf (no sincosf scratch). ----
    for (int idx = tid; idx < BM * 64; idx += 256) {
        const int s = idx >> 6, j = idx & 63, m = m0 + s;
        if (j < 46) {
            float x; int dsin, dcos;
            if (j < 30) {                       // pos: 10 bands x 3 coords
                const int l = j / 3, c = j - 3 * l;
                x = points[m * 3 + c] * (float)(1 << l);
                dsin = 3 + l * 6 + c; dcos = dsin + 3;
            } else if (j < 42) {                // dirs: 4 bands x 3 coords
                const int jj = j - 30, l = jj / 3, c = jj - 3 * l;
                x = dirsv[m * 3 + c] * (float)(1 << l);
                dsin = 66 + l * 6 + c; dcos = dsin + 3;
            } else {                            // time: 4 bands x 1
                const int l = j - 42;
                x = timev[m] * (float)(1 << l);
                dsin = 91 + 2 * l; dcos = dsin + 1;
            }
            E[s][dsin] = f2bf(sinf(x));
            E[s][dcos] = f2bf(cosf(x));
        } else {                                // passthroughs + zero pad
            int t = (j - 46) * 2;
#pragma unroll
            for (int u = 0; u < 2; u++, t++) {
                float v = 0.0f; int d;
                if (t < 3)       { d = t;        v = points[m * 3 + t]; }
                else if (t < 6)  { d = 60 + t;   v = dirsv[m * 3 + t - 3]; }  // 63..65
                else if (t == 6) { d = 90;       v = timev[m]; }
                else             { d = 92 + t; }                              // 99..127 = 0
                E[s][d] = f2bf(v);
            }
        }
    }
    bar_lgkm();

    // ---- static MLP ----
    layer256<4, true, ES>(&E[0][0],  wt + SW0, sb0, &Hb[0][0], HS, tid);
    layer256<8, true, HS>(&Hb[0][0], wt + SW1, sb1, &Hb[0][0], HS, tid);
    layer256<8, true, HS>(&Hb[0][0], wt + SW2, sb2, &Hb[0][0], HS, tid);
    layer256<8, true, HS>(&Hb[0][0], wt + SW3, sb3, &Hb[0][0], HS, tid);
    head256<4, 4>(&Hb[0][0], HS, wt + SW4, sb4, &so[0][0], tid);
    // (dynamic L0's bar_only orders these head reads of Hb vs its Hb overwrite)

    // ---- dynamic MLP ----
    layer256<4, true, ES>(&E[0][0],  wt + DW0, db0, &Hb[0][0], HS, tid);
    layer256<8, true, HS>(&Hb[0][0], wt + DW1, db1, &Hb[0][0], HS, tid);
    layer256<8, true, HS>(&Hb[0][0], wt + DW2, db2, &Hb[0][0], HS, tid);
    layer256<8, true, HS>(&Hb[0][0], wt + DW3, db3, &Hb[0][0], HS, tid);
    head256<5, 5>(&Hb[0][0], HS, wt + DW4, db4, &dn[0][0], tid);
    bar_lgkm();

    // ---- blend ----
    if (tid < BM) {
        const int s = tid, m = m0 + s;
        const float bw = sigm(dn[s][4]);
        const float sigma = (1.f - bw) * so[s][0] + bw * dn[s][0];
        const float r  = (1.f - bw) * sigm(so[s][1]) + bw * sigm(dn[s][1]);
        const float gg = (1.f - bw) * sigm(so[s][2]) + bw * sigm(dn[s][2]);
        const float bb = (1.f - bw) * sigm(so[s][3]) + bw * sigm(dn[s][3]);
        o_sigma[m] = sigma; o_r[m] = r; o_g[m] = gg; o_b[m] = bb; o_bw[m] = bw;
    }
}

// ---------------- compositing: one wave per ray, shuffle scan ----------------
__global__ __launch_bounds__(256)
void nerf_comp(const float* __restrict__ zv,
               const float* __restrict__ o_sigma, const float* __restrict__ o_r,
               const float* __restrict__ o_g, const float* __restrict__ o_b,
               const float* __restrict__ o_bw, float* __restrict__ out)
{
    const int ray  = blockIdx.x * 4 + (threadIdx.x >> 6);
    const int lane = threadIdx.x & 63;
    const int base = ray * SAMP;
    const int s0 = 2 * lane, s1 = s0 + 1;

    const float z0 = zv[base + s0];
    const float z1 = zv[base + s1];
    const float z2 = (lane < 63) ? zv[base + s1 + 1] : 0.0f;
    const float d0 = z1 - z0;
    const float d1 = (lane < 63) ? (z2 - z1) : 1e10f;

    const float sg0 = o_sigma[base + s0], sg1 = o_sigma[base + s1];
    const float a0 = 1.0f - expf(-sg0 * d0);
    const float a1 = 1.0f - expf(-sg1 * d1);
    const float f0 = 1.0f - a0 + 1e-10f;
    const float f1 = 1.0f - a1 + 1e-10f;

    float incl = f0 * f1;
#pragma unroll
    for (int dlt = 1; dlt < 64; dlt <<= 1) {
        const float t = __shfl_up(incl, dlt);
        if (lane >= dlt) incl *= t;
    }
    float ex = __shfl_up(incl, 1);
    if (lane == 0) ex = 1.0f;

    const float t0 = ex;
    const float t1 = ex * f0;
    const float w0 = a0 * t0, w1 = a1 * t1;

    const float bw0 = o_bw[base + s0], bw1 = o_bw[base + s1];
    out[OUT_W  + base + s0] = w0;               out[OUT_W  + base + s1] = w1;
    out[OUT_SW + base + s0] = (1.f - bw0) * w0; out[OUT_SW + base + s1] = (1.f - bw1) * w1;
    out[OUT_DW + base + s0] = bw0 * w0;         out[OUT_DW + base + s1] = bw1 * w1;

    float pr = w0 * o_r[base + s0] + w1 * o_r[base + s1];
    float pg = w0 * o_g[base + s0] + w1 * o_g[base + s1];
    float pb = w0 * o_b[base + s0] + w1 * o_b[base + s1];
    float pd = w0 * z0 + w1 * z1;
#pragma unroll
    for (int dlt = 32; dlt >= 1; dlt >>= 1) {
        pr += __shfl_down(pr, dlt);
        pg += __shfl_down(pg, dlt);
        pb += __shfl_down(pb, dlt);
        pd += __shfl_down(pd, dlt);
    }
    if (lane == 0) {
        out[OUT_RGB + ray * 3 + 0] = pr;
        out[OUT_RGB + ray * 3 + 1] = pg;
        out[OUT_RGB + ray * 3 + 2] = pb;
        out[OUT_DEPTH + ray] = pd;
    }
}

extern "C" void kernel_launch(void* const* d_in, const int* in_sizes, int n_in,
                              void* d_out, int out_size, void* d_ws, size_t ws_size,
                              hipStream_t stream)
{
    const float* points = (const float*)d_in[0];
    const float* dirsv  = (const float*)d_in[1];
    const float* zvals  = (const float*)d_in[2];
    const float* timev  = (const float*)d_in[3];

    const float *sW[5], *sb[5], *dW[5], *db[5];
    if (in_sizes[6] == 99 * 256) {
        for (int i = 0; i < 5; i++) {   // interleaved (sW_i, sb_i, dW_i, db_i)
            sW[i] = (const float*)d_in[4 + 4 * i + 0];
            sb[i] = (const float*)d_in[4 + 4 * i + 1];
            dW[i] = (const float*)d_in[4 + 4 * i + 2];
            db[i] = (const float*)d_in[4 + 4 * i + 3];
        }
    } else {
        for (int i = 0; i < 5; i++) {   // all static then all dynamic
            sW[i] = (const float*)d_in[4 + 2 * i + 0];
            sb[i] = (const float*)d_in[4 + 2 * i + 1];
            dW[i] = (const float*)d_in[14 + 2 * i + 0];
            db[i] = (const float*)d_in[14 + 2 * i + 1];
        }
    }

    // ws layout: bf16 weights (933888 B) then 5 fp32 per-sample arrays (1 MB each)
    short* wt = (short*)d_ws;
    float* ws = (float*)((char*)d_ws + (size_t)WTOT * 2);
    float* o_sigma = ws;
    float* o_r  = ws + (size_t)MTOT * 1;
    float* o_g  = ws + (size_t)MTOT * 2;
    float* o_b  = ws + (size_t)MTOT * 3;
    float* o_bw = ws + (size_t)MTOT * 4;

    prep_weights<<<(WTOT + 255) / 256, 256, 0, stream>>>(
        sW[0], sW[1], sW[2], sW[3], sW[4], dW[0], dW[1], dW[2], dW[3], dW[4], wt);

    nerf_mlp<<<MTOT / BM, 256, 0, stream>>>(points, dirsv, timev, wt,
        sb[0], sb[1], sb[2], sb[3], sb[4], db[0], db[1], db[2], db[3], db[4],
        o_sigma, o_r, o_g, o_b, o_bw);

    nerf_comp<<<RAYS / 4, 256, 0, stream>>>(zvals, o_sigma, o_r, o_g, o_b, o_bw,
                                            (float*)d_out);
}